// Round 15
// baseline (181.563 us; speedup 1.0000x reference)
//
#include <hip/hip_runtime.h>
#include <hip/hip_fp16.h>
#include <math.h>

#define B_ 4
#define D_ 96
#define H_ 64
#define W_ 64
#define L_ 4096
#define K_ 4
#define N_ 16
#define R_ 6
#define C_ 38   // R + 2N
#define SSX 128            // chunks per sequence
#define CLSX (L_ / SSX)    // 32
#define CH_ (B_ * K_ * D_ * N_)  // 24576 scan channels

#if defined(__has_builtin)
#if __has_builtin(__builtin_amdgcn_exp2f)
#define EXP2F(x) __builtin_amdgcn_exp2f(x)
#else
#define EXP2F(x) exp2f(x)
#endif
#else
#define EXP2F(x) exp2f(x)
#endif
#define LOG2E 1.44269504f

// XOR swizzle for s_xs lt-index (quad-preserving).
#define SW(d) ((((d) >> 2) & 7) << 2)

__device__ __forceinline__ int src_idx(int k, int l) {
    int m = (k >= 2) ? (L_ - 1 - l) : l;
    if (k & 1) return ((m & 63) << 6) | (m >> 6);
    return m;
}

__device__ __forceinline__ float softplus_f(float a) {
    return (a > 15.f) ? a : __logf(1.f + __expf(a));
}

__device__ __forceinline__ ushort f2h(float v) {
    return __half_as_ushort(__float2half_rn(v));
}

// Load 8 halfs (16B aligned) -> 8 floats.
__device__ __forceinline__ void load_h8(const __half* p, float* out) {
    uint4 raw = *(const uint4*)p;
    const __half2* h2 = (const __half2*)&raw;
#pragma unroll
    for (int i = 0; i < 4; ++i) {
        float2 f = __half22float2(h2[i]);
        out[2 * i] = f.x;
        out[2 * i + 1] = f.y;
    }
}

// Store 8 floats -> 8 halfs (16B aligned).
__device__ __forceinline__ void store_h8(__half* p, const float* v) {
    uint4 raw;
    __half2* h2 = (__half2*)&raw;
#pragma unroll
    for (int i = 0; i < 4; ++i)
        h2[i] = __floats2half2_rn(v[2 * i], v[2 * i + 1]);
    *(uint4*)p = raw;
}

// Load 4 halfs (8B aligned) -> float4.
__device__ __forceinline__ float4 load_h4(const __half* p) {
    uint2 raw = *(const uint2*)p;
    const __half2* h2 = (const __half2*)&raw;
    float2 a = __half22float2(h2[0]);
    float2 b = __half22float2(h2[1]);
    return make_float4(a.x, a.y, b.x, b.y);
}

// ---------------------------------------------------------------------------
// Kernel T: build xs2[2][B][L][96] in fp16.
// ---------------------------------------------------------------------------
__global__ __launch_bounds__(256) void transpose_kernel(
    const float* __restrict__ x,    // (B,96,64,64) fp32
    __half* __restrict__ xs2)       // (2,B,L,96) fp16
{
    int bid = blockIdx.x;                // B * 3 * 64 = 768
    int b = bid / (3 * 64);
    int rest = bid % (3 * 64);
    int dblk = rest / 64, lblk = rest % 64;
    int d0 = dblk * 32;
    int l0 = lblk * 64;
    int tid = threadIdx.x;

    __shared__ float s_t[32][65];

    for (int i = tid; i < 32 * 64; i += 256) {
        int d = i >> 6, l = i & 63;
        s_t[d][l] = x[((long)b * D_ + d0 + d) * L_ + l0 + l];
    }
    __syncthreads();

    for (int i = tid; i < 64 * 32; i += 256) {
        int l = i >> 5, d = i & 31;
        __half v = __float2half_rn(s_t[d][l]);
        xs2[((long)b * L_ + l0 + l) * D_ + d0 + d] = v;                       // p=0
        xs2[((long)(B_ + b) * L_ + l * 64 + lblk) * D_ + d0 + d] = v;        // p=1
    }
}

// ---------------------------------------------------------------------------
// Kernel A: projections + fused chunk-local scan (pass 1). 384 threads:
//  - GEMM 2x4 register tiles, 320 active threads (6 waves vs R14's 2.5)
//  - delta phase: exactly 1 item/thread
//  - fused scan: ALL 384 threads (2 chunks x 96 dd x 2 n-halves, 8 states)
// Summaries (pA,h) stored fp16.
// ---------------------------------------------------------------------------
__global__ __launch_bounds__(384) void proj_scan_kernel(
    const __half* __restrict__ xs2,  // (2,B,L,96) fp16
    const float* __restrict__ xpw,   // (K,38,96)
    const float* __restrict__ wdt,   // (K,96,6)
    const float* __restrict__ bdt,   // (K,96)
    const float* __restrict__ A_logs,// (K*D,16)
    __half* __restrict__ delta,      // (B*K, L, 96) fp16
    __half* __restrict__ Bsb,        // (B*K, L, 16) fp16
    __half* __restrict__ Csb,        // (B*K, L, 16) fp16
    __half* __restrict__ pAarr,      // [SSX][CH] fp16
    __half* __restrict__ hharr)      // [SSX][CH] fp16
{
    const int TL = 64;
    const int tiles = L_ / TL;               // 64
    int bid = blockIdx.x;                    // B*K*tiles = 1024
    int bk = bid / tiles;
    int tile = bid % tiles;
    int b = bk / K_, k = bk % K_;
    int l0 = tile * TL;
    int tid = threadIdx.x;

    __shared__ __align__(16) float  s_wpT[D_ * 40];    // [d][cp]   15.4 KB
    __shared__ __align__(16) __half s_xs[D_ * 68];     // [d][lt^SW(d)] 13.1 KB
    __shared__ __align__(16) float  s_wdt[R_ * D_];    // [r][d]     2.3 KB
    __shared__ __align__(16) float  s_bias[D_];
    __shared__ __align__(16) float  s_dts[R_ * 68];    // [r][lt]    1.6 KB
    __shared__ __align__(16) float  s_B[TL * N_];      // [lt][n]    4.0 KB

    for (int i = tid; i < C_ * D_; i += 384) {
        int d = i / C_, c = i % C_;
        int cp = (c < 6) ? c : c + 2;
        s_wpT[d * 40 + cp] = xpw[(k * C_ + c) * D_ + d];
    }
    for (int i = tid; i < 96; i += 384) {
        s_wpT[i * 40 + 6] = 0.f;
        s_wpT[i * 40 + 7] = 0.f;
    }
    for (int i = tid; i < R_ * D_; i += 384) {
        int r = i / D_, d = i % D_;
        s_wdt[i] = wdt[(k * D_ + d) * R_ + r];
    }
    if (tid < D_) s_bias[tid] = bdt[k * D_ + tid];

    const __half* xsp = xs2 + (long)((k & 1) * B_ + b) * L_ * D_;
    for (int i = tid; i < TL * 24; i += 384) {
        int lt = i / 24, dq = i % 24;
        int row = (k < 2) ? (l0 + lt) : (L_ - 1 - l0 - lt);
        uint2 raw = *(const uint2*)(xsp + (long)row * D_ + dq * 4);
        const __half* hv = (const __half*)&raw;
        int d0 = dq * 4;
        s_xs[(d0 + 0) * 68 + (lt ^ SW(d0 + 0))] = hv[0];
        s_xs[(d0 + 1) * 68 + (lt ^ SW(d0 + 1))] = hv[1];
        s_xs[(d0 + 2) * 68 + (lt ^ SW(d0 + 2))] = hv[2];
        s_xs[(d0 + 3) * 68 + (lt ^ SW(d0 + 3))] = hv[3];
    }
    __syncthreads();

    long base = (long)bk * L_ + l0;

    // GEMM: 2x4 register tiles; 24 c-tiles x 16 lt-tiles, ct==3 is pad (skip).
    int ct = tid >> 4;                 // 0..23
    int lt4 = (tid & 15) * 4;
    if (ct < 20 && ct != 3) {
        int cp0 = ct * 2;
        float acc[2][4];
#pragma unroll
        for (int i = 0; i < 2; ++i)
#pragma unroll
            for (int j = 0; j < 4; ++j) acc[i][j] = 0.f;
#pragma unroll 4
        for (int d = 0; d < D_; ++d) {
            float2 wv = *(const float2*)(&s_wpT[d * 40 + cp0]);
            float4 xv = load_h4(&s_xs[d * 68 + (lt4 ^ SW(d))]);
            float wa[2] = {wv.x, wv.y};
            float xa[4] = {xv.x, xv.y, xv.z, xv.w};
#pragma unroll
            for (int ci = 0; ci < 2; ++ci)
#pragma unroll
                for (int li = 0; li < 4; ++li)
                    acc[ci][li] += wa[ci] * xa[li];
        }
        if (ct < 3) {
#pragma unroll
            for (int ci = 0; ci < 2; ++ci)
                *(float4*)(&s_dts[(cp0 + ci) * 68 + lt4]) =
                    make_float4(acc[ci][0], acc[ci][1], acc[ci][2], acc[ci][3]);
        } else if (ct < 12) {
            int n0 = cp0 - 8;
#pragma unroll
            for (int li = 0; li < 4; ++li) {
                ushort2 hv;
                hv.x = f2h(acc[0][li]); hv.y = f2h(acc[1][li]);
                *(ushort2*)(&Bsb[(base + lt4 + li) * N_ + n0]) = hv;
                *(float2*)(&s_B[(lt4 + li) * N_ + n0]) =
                    make_float2(acc[0][li], acc[1][li]);
            }
        } else {
            int n0 = cp0 - 24;
#pragma unroll
            for (int li = 0; li < 4; ++li) {
                ushort2 hv;
                hv.x = f2h(acc[0][li]); hv.y = f2h(acc[1][li]);
                *(ushort2*)(&Csb[(base + lt4 + li) * N_ + n0]) = hv;
            }
        }
    }
    __syncthreads();

    // delta phase: exactly one 4-wide item per thread (24 x 16 = 384)
    {
        int dt = tid % 24, lt4b = (tid / 24) * 4;
        int d0 = dt * 4;
        float4 bias = *(const float4*)(&s_bias[d0]);
        float acc[4][4];
#pragma unroll
        for (int li = 0; li < 4; ++li) {
            acc[li][0] = bias.x; acc[li][1] = bias.y;
            acc[li][2] = bias.z; acc[li][3] = bias.w;
        }
#pragma unroll
        for (int r = 0; r < R_; ++r) {
            float4 wv = *(const float4*)(&s_wdt[r * D_ + d0]);
            float4 tv = *(const float4*)(&s_dts[r * 68 + lt4b]);
            float wa[4] = {wv.x, wv.y, wv.z, wv.w};
            float ta[4] = {tv.x, tv.y, tv.z, tv.w};
#pragma unroll
            for (int li = 0; li < 4; ++li)
#pragma unroll
                for (int di = 0; di < 4; ++di)
                    acc[li][di] += ta[li] * wa[di];
        }
#pragma unroll
        for (int li = 0; li < 4; ++li) {
            ushort4 o;
            o.x = f2h(softplus_f(acc[li][0]));
            o.y = f2h(softplus_f(acc[li][1]));
            o.z = f2h(softplus_f(acc[li][2]));
            o.w = f2h(softplus_f(acc[li][3]));
            *(ushort4*)(&delta[(base + lt4b + li) * D_ + d0]) = o;
        }
    }

    // Fused chunk scan (pass 1): all 384 threads.
    // thread = (sub-chunk, dd, n-half); 8 states each.
    {
        int sub = tid / 192;           // chunk within tile
        int r = tid % 192;
        int dd = r >> 1;
        int half = r & 1;
        int n0h = half * 8;
        int j = tile * 2 + sub;
        int kd = k * D_ + dd;

        float A2[8];
        {
            const float4* ap = (const float4*)(A_logs + kd * N_ + n0h);
            float4 a0 = ap[0], a1 = ap[1];
            A2[0] = -__expf(a0.x) * LOG2E; A2[1] = -__expf(a0.y) * LOG2E;
            A2[2] = -__expf(a0.z) * LOG2E; A2[3] = -__expf(a0.w) * LOG2E;
            A2[4] = -__expf(a1.x) * LOG2E; A2[5] = -__expf(a1.y) * LOG2E;
            A2[6] = -__expf(a1.z) * LOG2E; A2[7] = -__expf(a1.w) * LOG2E;
        }
        float wdtr[R_];
#pragma unroll
        for (int rr = 0; rr < R_; ++rr) wdtr[rr] = s_wdt[rr * D_ + dd];
        float biasv = s_bias[dd];
        int sw = SW(dd);

        float h[8];
#pragma unroll
        for (int i = 0; i < 8; ++i) h[i] = 0.f;
        float sdel = 0.f;

#pragma unroll 4
        for (int t = 0; t < CLSX; ++t) {
            int lt = sub * CLSX + t;
            float acc = biasv;
#pragma unroll
            for (int rr = 0; rr < R_; ++rr) acc += wdtr[rr] * s_dts[rr * 68 + lt];
            float del = softplus_f(acc);
            float u = __half2float(s_xs[dd * 68 + (lt ^ sw)]);
            float Bv[8];
            *(float4*)(Bv + 0) = *(const float4*)(&s_B[lt * N_ + n0h]);
            *(float4*)(Bv + 4) = *(const float4*)(&s_B[lt * N_ + n0h + 4]);
            sdel += del;
            float delu = del * u;
#pragma unroll
            for (int i = 0; i < 8; ++i) {
                float dA = EXP2F(del * A2[i]);
                h[i] = h[i] * dA + delu * Bv[i];
            }
        }

        long sbase = (long)j * CH_ + (long)(bk * D_ + dd) * N_ + n0h;
        float pv[8];
#pragma unroll
        for (int i = 0; i < 8; ++i) pv[i] = EXP2F(A2[i] * sdel);
        store_h8(pAarr + sbase, pv);
        store_h8(hharr + sbase, h);
    }
}

// ---------------------------------------------------------------------------
// Pass 2: sequential combine over SSX chunk summaries (in-place, fp16 io).
// ---------------------------------------------------------------------------
__global__ __launch_bounds__(256) void scan_combine(
    const __half* __restrict__ pAarr,
    __half* __restrict__ hharr)
{
    int c = blockIdx.x * 256 + threadIdx.x;
    float h = 0.f;
#pragma unroll 16
    for (int j = 0; j < SSX; ++j) {
        long idx = (long)j * CH_ + c;
        float tmp = __half2float(hharr[idx]);
        float pa  = __half2float(pAarr[idx]);
        hharr[idx] = __float2half_rn(h);
        h = tmp + pa * h;
    }
}

// ---------------------------------------------------------------------------
// Pass 3: paired-direction re-scan, 8 states/thread; all-fp16 inputs.
// ---------------------------------------------------------------------------
__global__ __launch_bounds__(384) void scan_part2_pair(
    const float* __restrict__ A_logs,
    const float* __restrict__ Ds,
    const __half* __restrict__ xs2,
    const __half* __restrict__ delta,
    const __half* __restrict__ Bsb,
    const __half* __restrict__ Csb,
    const __half* __restrict__ hharr,
    float* __restrict__ ypair)   // (2, B, L, 96)
{
    __shared__ float s_y[2][CLSX][D_];   // 24.6 KB

    int bid = blockIdx.x;                // B*2*SSX = 1024
    int b = bid / (2 * SSX);
    int rest = bid % (2 * SSX);
    int p = rest / SSX;
    int j = rest % SSX;
    int tid = threadIdx.x;
    int g = tid / 192;
    int r = tid % 192;
    int dd = r >> 1;
    int half = r & 1;
    int n0 = half * 8;

    int kdir = p + 2 * g;
    int bk = b * K_ + kdir;
    int jj = g ? (SSX - 1 - j) : j;
    int l0s = jj * CLSX;
    int kd = kdir * D_ + dd;

    float A2[8];
    {
        const float4* ap = (const float4*)(A_logs + kd * N_ + n0);
        float4 a0 = ap[0], a1 = ap[1];
        A2[0] = -__expf(a0.x) * LOG2E; A2[1] = -__expf(a0.y) * LOG2E;
        A2[2] = -__expf(a0.z) * LOG2E; A2[3] = -__expf(a0.w) * LOG2E;
        A2[4] = -__expf(a1.x) * LOG2E; A2[5] = -__expf(a1.y) * LOG2E;
        A2[6] = -__expf(a1.z) * LOG2E; A2[7] = -__expf(a1.w) * LOG2E;
    }
    float Dv = Ds[kd];

    const __half* dp = delta + ((long)bk * L_ + l0s) * D_ + dd;
    const __half* bp = Bsb + ((long)bk * L_ + l0s) * N_ + n0;
    const __half* cp = Csb + ((long)bk * L_ + l0s) * N_ + n0;
    const __half* xsp = xs2 + (long)(p * B_ + b) * L_ * D_;
    long urow0 = g ? ((long)j * CLSX + CLSX - 1) : (long)l0s;
    long ustep = g ? -D_ : D_;
    const __half* up = xsp + urow0 * D_ + dd;

    float h[8];
    load_h8(hharr + (long)jj * CH_ + (long)(bk * D_ + dd) * N_ + n0, h);

#pragma unroll 4
    for (int t = 0; t < CLSX; ++t) {
        float del = __half2float(dp[(long)t * D_]);
        float u   = __half2float(up[(long)t * ustep]);
        float Bv[8], Cv[8];
        load_h8(bp + t * N_, Bv);
        load_h8(cp + t * N_, Cv);
        float delu = del * u;
        float yv = 0.f;
#pragma unroll
        for (int i = 0; i < 8; ++i) {
            float dA = EXP2F(del * A2[i]);
            h[i] = h[i] * dA + delu * Bv[i];
            yv += h[i] * Cv[i];
        }
        yv += __shfl_xor(yv, 1);   // sum the two n-halves (adjacent lanes)
        if (half == 0) {
            int tpos = g ? (CLSX - 1 - t) : t;
            s_y[g][tpos][dd] = yv + Dv * u;
        }
    }
    __syncthreads();

    float* yo = ypair + ((long)(p * B_ + b) * L_ + (long)j * CLSX) * D_;
    for (int i = tid; i < CLSX * 24; i += 384) {
        int lt = i / 24, dq = i % 24;
        int d0 = dq * 4;
        float4 o = make_float4(s_y[0][lt][d0 + 0] + s_y[1][lt][d0 + 0],
                               s_y[0][lt][d0 + 1] + s_y[1][lt][d0 + 1],
                               s_y[0][lt][d0 + 2] + s_y[1][lt][d0 + 2],
                               s_y[0][lt][d0 + 3] + s_y[1][lt][d0 + 3]);
        *(float4*)(yo + (long)lt * D_ + d0) = o;
    }
}

// ---------------------------------------------------------------------------
// Final: merge the two pair buffers (p=1 via transpose map) + LayerNorm.
// ---------------------------------------------------------------------------
__global__ __launch_bounds__(256) void ln_merge_kernel(
    const float* __restrict__ ypair,  // (2,B,L,96)
    const float* __restrict__ lnw,
    const float* __restrict__ lnb,
    float* __restrict__ out)          // (B,L,96)
{
    int wid = (blockIdx.x * 256 + threadIdx.x) >> 6;
    int lane = threadIdx.x & 63;
    int b = wid / L_;
    int m = wid % L_;
    int mt = ((m & 63) << 6) | (m >> 6);

    const float* y0 = ypair + ((long)b * L_ + m) * D_;
    const float* y1 = ypair + ((long)(B_ + b) * L_ + mt) * D_;

    float v0 = y0[lane] + y1[lane];
    float v1 = (lane < 32) ? (y0[64 + lane] + y1[64 + lane]) : 0.f;

    float s  = v0 + v1;
    float s2 = v0 * v0 + v1 * v1;
#pragma unroll
    for (int mm = 1; mm < 64; mm <<= 1) {
        s  += __shfl_xor(s, mm);
        s2 += __shfl_xor(s2, mm);
    }
    float mu  = s * (1.f / D_);
    float var = s2 * (1.f / D_) - mu * mu;
    float rstd = rsqrtf(var + 1e-5f);

    long obase = (long)wid * D_;
    out[obase + lane] = (v0 - mu) * rstd * lnw[lane] + lnb[lane];
    if (lane < 32)
        out[obase + 64 + lane] = (v1 - mu) * rstd * lnw[64 + lane] + lnb[64 + lane];
}

// ---------------------------------------------------------------------------
// Fallback path (only if ws too small): fp32 proj + serial scan + merge.
// ---------------------------------------------------------------------------
__global__ __launch_bounds__(256) void proj_legacy(
    const float* __restrict__ x,
    const float* __restrict__ xpw,
    const float* __restrict__ wdt,
    const float* __restrict__ bdt,
    float* __restrict__ delta,
    float* __restrict__ Bsb,
    float* __restrict__ Csb)
{
    const int TL = 64;
    const int tiles = L_ / TL;
    int bid = blockIdx.x;
    int bk = bid / tiles;
    int tile = bid % tiles;
    int b = bk / K_, k = bk % K_;
    int l0 = tile * TL;
    int tid = threadIdx.x;

    __shared__ float s_wp[C_ * D_];
    __shared__ float s_wdt[R_ * D_];
    __shared__ float s_bias[D_];
    __shared__ float s_xs[D_ * (TL + 1)];
    __shared__ float s_xdbl[C_ * (TL + 1)];

    for (int i = tid; i < C_ * D_; i += 256) s_wp[i] = xpw[k * C_ * D_ + i];
    for (int i = tid; i < R_ * D_; i += 256) {
        int r = i / D_, d = i % D_;
        s_wdt[i] = wdt[(k * D_ + d) * R_ + r];
    }
    if (tid < D_) s_bias[tid] = bdt[k * D_ + tid];
    for (int i = tid; i < D_ * TL; i += 256) {
        int d = i / TL, lt = i % TL;
        s_xs[d * (TL + 1) + lt] = x[(b * D_ + d) * L_ + src_idx(k, l0 + lt)];
    }
    __syncthreads();

    for (int idx = tid; idx < C_ * TL; idx += 256) {
        int c = idx / TL, lt = idx % TL;
        const float* wr = &s_wp[c * D_];
        float acc = 0.f;
#pragma unroll 8
        for (int d = 0; d < D_; ++d) acc += wr[d] * s_xs[d * (TL + 1) + lt];
        s_xdbl[c * (TL + 1) + lt] = acc;
    }
    __syncthreads();

    long base = (long)bk * L_ + l0;
    for (int idx = tid; idx < TL * D_; idx += 256) {
        int lt = idx / D_, d = idx % D_;
        float acc = s_bias[d];
#pragma unroll
        for (int r = 0; r < R_; ++r)
            acc += s_wdt[r * D_ + d] * s_xdbl[r * (TL + 1) + lt];
        delta[(base + lt) * D_ + d] = softplus_f(acc);
    }
    for (int idx = tid; idx < TL * 2 * N_; idx += 256) {
        int lt = idx / (2 * N_), c2 = idx % (2 * N_);
        float v = s_xdbl[(R_ + c2) * (TL + 1) + lt];
        if (c2 < N_) Bsb[(base + lt) * N_ + c2] = v;
        else         Csb[(base + lt) * N_ + (c2 - N_)] = v;
    }
}

__global__ __launch_bounds__(64) void scan_serial(
    const float* __restrict__ x,
    const float* __restrict__ A_logs,
    const float* __restrict__ Ds,
    const float* __restrict__ delta,
    const float* __restrict__ Bsb,
    const float* __restrict__ Csb,
    float* __restrict__ ys)
{
    const int chans = D_ / 4;
    int bid = blockIdx.x;
    int bk = bid / chans;
    int d0 = (bid % chans) * 4;
    int b = bk / K_, k = bk % K_;
    int lane = threadIdx.x;
    int g = lane >> 4, n = lane & 15;
    int d = d0 + g;
    int kd = k * D_ + d;

    float A  = -__expf(A_logs[kd * N_ + n]);
    float Dv = Ds[kd];
    const float* dptr = delta + ((long)bk * L_) * D_ + d;
    const float* bptr = Bsb + (long)bk * L_ * N_ + n;
    const float* cptr = Csb + (long)bk * L_ * N_ + n;
    const float* xptr = x + ((long)b * D_ + d) * L_;
    float* yptr = ys + ((long)bk * L_) * D_ + d;

    float h = 0.f;
#pragma unroll 4
    for (int l = 0; l < L_; ++l) {
        float del = dptr[(long)l * D_];
        float u   = xptr[src_idx(k, l)];
        float Bt  = bptr[l * N_];
        float Ct  = cptr[l * N_];
        float dA  = __expf(del * A);
        h = h * dA + del * u * Bt;
        float yv = h * Ct;
        yv += __shfl_xor(yv, 1);
        yv += __shfl_xor(yv, 2);
        yv += __shfl_xor(yv, 4);
        yv += __shfl_xor(yv, 8);
        if (n == 0) yptr[(long)l * D_] = yv + Dv * u;
    }
}

__global__ __launch_bounds__(256) void merge_ln_kernel(
    const float* __restrict__ ys,
    const float* __restrict__ lnw,
    const float* __restrict__ lnb,
    float* __restrict__ out)
{
    int wid = (blockIdx.x * 256 + threadIdx.x) >> 6;
    int lane = threadIdx.x & 63;
    int b = wid / L_;
    int l = wid % L_;
    int lt = ((l & 63) << 6) | (l >> 6);

    long base0 = ((long)(b * K_ + 0) * L_ + l) * D_;
    long base2 = ((long)(b * K_ + 2) * L_ + (L_ - 1 - l)) * D_;
    long base1 = ((long)(b * K_ + 1) * L_ + lt) * D_;
    long base3 = ((long)(b * K_ + 3) * L_ + (L_ - 1 - lt)) * D_;

    int dA = lane;
    int dB = lane + 64;
    float v0 = ys[base0 + dA] + ys[base2 + dA] + ys[base1 + dA] + ys[base3 + dA];
    float v1 = 0.f;
    if (dB < D_)
        v1 = ys[base0 + dB] + ys[base2 + dB] + ys[base1 + dB] + ys[base3 + dB];

    float s  = v0 + v1;
    float s2 = v0 * v0 + v1 * v1;
#pragma unroll
    for (int m = 1; m < 64; m <<= 1) {
        s  += __shfl_xor(s, m);
        s2 += __shfl_xor(s2, m);
    }
    float mu  = s * (1.f / D_);
    float var = s2 * (1.f / D_) - mu * mu;
    float rstd = rsqrtf(var + 1e-5f);

    long obase = ((long)b * L_ + l) * D_;
    out[obase + dA] = (v0 - mu) * rstd * lnw[dA] + lnb[dA];
    if (dB < D_)
        out[obase + dB] = (v1 - mu) * rstd * lnw[dB] + lnb[dB];
}

extern "C" void kernel_launch(void* const* d_in, const int* in_sizes, int n_in,
                              void* d_out, int out_size, void* d_ws, size_t ws_size,
                              hipStream_t stream) {
    const float* x      = (const float*)d_in[0];
    const float* xpw    = (const float*)d_in[1];
    const float* wdt    = (const float*)d_in[2];
    const float* bdt    = (const float*)d_in[3];
    const float* A_logs = (const float*)d_in[4];
    const float* Ds     = (const float*)d_in[5];
    const float* lnw    = (const float*)d_in[6];
    const float* lnb    = (const float*)d_in[7];
    float* out = (float*)d_out;

    const long n_delta = (long)B_ * K_ * L_ * D_;   // 6,291,456
    const long n_bc    = (long)B_ * K_ * L_ * N_;   // 1,048,576
    const long n_bld   = (long)B_ * L_ * D_;        // 1,572,864
    const long n_sum   = (long)SSX * CH_;           // 3,145,728

    // Byte layout: fp16 delta/B/C/xs2/summaries; fp32 ypair. 16B-aligned.
    char* wsb = (char*)d_ws;
    __half* delta = (__half*)wsb;                                  // 12.6 MB
    __half* Bsb   = (__half*)(wsb + n_delta * 2);                  //  2.1 MB
    __half* Csb   = (__half*)(wsb + n_delta * 2 + n_bc * 2);       //  2.1 MB
    __half* xs2   = (__half*)(wsb + n_delta * 2 + n_bc * 4);       //  6.3 MB
    float*  ypair = (float*)(wsb + n_delta * 2 + n_bc * 4 + 2 * n_bld * 2); // 12.6 MB
    __half* hharr = (__half*)((char*)ypair + 2 * n_bld * 4);       //  6.3 MB
    __half* pAarr = (__half*)ypair;  // alias: pA dead before ypair written
    size_t need = (size_t)(n_delta * 2 + n_bc * 4 + 2 * n_bld * 2) +
                  (size_t)(2 * n_bld) * 4 + (size_t)n_sum * 2;     // ~42 MB

    if (ws_size >= need) {
        transpose_kernel<<<B_ * 3 * 64, 256, 0, stream>>>(x, xs2);
        proj_scan_kernel<<<B_ * K_ * (L_ / 64), 384, 0, stream>>>(
            xs2, xpw, wdt, bdt, A_logs, delta, Bsb, Csb, pAarr, hharr);
        scan_combine<<<CH_ / 256, 256, 0, stream>>>(pAarr, hharr);
        scan_part2_pair<<<B_ * 2 * SSX, 384, 0, stream>>>(
            A_logs, Ds, xs2, delta, Bsb, Csb, hharr, ypair);
        ln_merge_kernel<<<(B_ * L_) / 4, 256, 0, stream>>>(ypair, lnw, lnb, out);
    } else {
        // Compact fp32 serial fallback (~58.7 MB layout)
        float* ws = (float*)d_ws;
        float* deltaf = ws;
        float* Bsb2   = deltaf + n_delta;
        float* Csb2   = Bsb2 + n_bc;
        float* ys2    = Csb2 + n_bc;
        proj_legacy<<<B_ * K_ * (L_ / 64), 256, 0, stream>>>(
            x, xpw, wdt, bdt, deltaf, Bsb2, Csb2);
        scan_serial<<<B_ * K_ * (D_ / 4), 64, 0, stream>>>(
            x, A_logs, Ds, deltaf, Bsb2, Csb2, ys2);
        merge_ln_kernel<<<(B_ * L_) / 4, 256, 0, stream>>>(ys2, lnw, lnb, out);
    }
}

// Round 16
// 170.492 us; speedup vs baseline: 1.0649x; 1.0649x over previous
//
#include <hip/hip_runtime.h>
#include <hip/hip_fp16.h>
#include <math.h>

#define B_ 4
#define D_ 96
#define H_ 64
#define W_ 64
#define L_ 4096
#define K_ 4
#define N_ 16
#define R_ 6
#define C_ 38   // R + 2N
#define SSX 128            // chunks per sequence
#define CLSX (L_ / SSX)    // 32
#define CH_ (B_ * K_ * D_ * N_)  // 24576 scan channels

#if defined(__has_builtin)
#if __has_builtin(__builtin_amdgcn_exp2f)
#define EXP2F(x) __builtin_amdgcn_exp2f(x)
#else
#define EXP2F(x) exp2f(x)
#endif
#else
#define EXP2F(x) exp2f(x)
#endif
#define LOG2E 1.44269504f

// XOR swizzle for s_xs lt-index (quad-preserving).
#define SW(d) ((((d) >> 2) & 7) << 2)

__device__ __forceinline__ int src_idx(int k, int l) {
    int m = (k >= 2) ? (L_ - 1 - l) : l;
    if (k & 1) return ((m & 63) << 6) | (m >> 6);
    return m;
}

__device__ __forceinline__ float softplus_f(float a) {
    return (a > 15.f) ? a : __logf(1.f + __expf(a));
}

__device__ __forceinline__ ushort f2h(float v) {
    return __half_as_ushort(__float2half_rn(v));
}

// Load 8 halfs (16B aligned) -> 8 floats.
__device__ __forceinline__ void load_h8(const __half* p, float* out) {
    uint4 raw = *(const uint4*)p;
    const __half2* h2 = (const __half2*)&raw;
#pragma unroll
    for (int i = 0; i < 4; ++i) {
        float2 f = __half22float2(h2[i]);
        out[2 * i] = f.x;
        out[2 * i + 1] = f.y;
    }
}

// Store 8 floats -> 8 halfs (16B aligned).
__device__ __forceinline__ void store_h8(__half* p, const float* v) {
    uint4 raw;
    __half2* h2 = (__half2*)&raw;
#pragma unroll
    for (int i = 0; i < 4; ++i)
        h2[i] = __floats2half2_rn(v[2 * i], v[2 * i + 1]);
    *(uint4*)p = raw;
}

// Load 4 halfs (8B aligned) -> float4.
__device__ __forceinline__ float4 load_h4(const __half* p) {
    uint2 raw = *(const uint2*)p;
    const __half2* h2 = (const __half2*)&raw;
    float2 a = __half22float2(h2[0]);
    float2 b = __half22float2(h2[1]);
    return make_float4(a.x, a.y, b.x, b.y);
}

// ---------------------------------------------------------------------------
// Kernel T: build xs2[2][B][L][96] in fp16.
// ---------------------------------------------------------------------------
__global__ __launch_bounds__(256) void transpose_kernel(
    const float* __restrict__ x,    // (B,96,64,64) fp32
    __half* __restrict__ xs2)       // (2,B,L,96) fp16
{
    int bid = blockIdx.x;                // B * 3 * 64 = 768
    int b = bid / (3 * 64);
    int rest = bid % (3 * 64);
    int dblk = rest / 64, lblk = rest % 64;
    int d0 = dblk * 32;
    int l0 = lblk * 64;
    int tid = threadIdx.x;

    __shared__ float s_t[32][65];

    for (int i = tid; i < 32 * 64; i += 256) {
        int d = i >> 6, l = i & 63;
        s_t[d][l] = x[((long)b * D_ + d0 + d) * L_ + l0 + l];
    }
    __syncthreads();

    for (int i = tid; i < 64 * 32; i += 256) {
        int l = i >> 5, d = i & 31;
        __half v = __float2half_rn(s_t[d][l]);
        xs2[((long)b * L_ + l0 + l) * D_ + d0 + d] = v;                       // p=0
        xs2[((long)(B_ + b) * L_ + l * 64 + lblk) * D_ + d0 + d] = v;        // p=1
    }
}

// ---------------------------------------------------------------------------
// Kernel A: projections + fused chunk-local scan (pass 1). R14 structure
// (256 thr, 4x4 GEMM @160, 192-thr 16-state scan) + fp16 summaries.
// ---------------------------------------------------------------------------
__global__ __launch_bounds__(256) void proj_scan_kernel(
    const __half* __restrict__ xs2,  // (2,B,L,96) fp16
    const float* __restrict__ xpw,   // (K,38,96)
    const float* __restrict__ wdt,   // (K,96,6)
    const float* __restrict__ bdt,   // (K,96)
    const float* __restrict__ A_logs,// (K*D,16)
    __half* __restrict__ delta,      // (B*K, L, 96) fp16
    __half* __restrict__ Bsb,        // (B*K, L, 16) fp16
    __half* __restrict__ Csb,        // (B*K, L, 16) fp16
    __half* __restrict__ pAarr,      // [SSX][CH] fp16
    __half* __restrict__ hharr)      // [SSX][CH] fp16
{
    const int TL = 64;
    const int tiles = L_ / TL;               // 64
    int bid = blockIdx.x;                    // B*K*tiles = 1024
    int bk = bid / tiles;
    int tile = bid % tiles;
    int b = bk / K_, k = bk % K_;
    int l0 = tile * TL;
    int tid = threadIdx.x;

    __shared__ __align__(16) float  s_wpT[D_ * 40];    // [d][cp]   15.4 KB
    __shared__ __align__(16) __half s_xs[D_ * 68];     // [d][lt^SW(d)] 13.1 KB
    __shared__ __align__(16) float  s_wdt[R_ * D_];    // [r][d]     2.3 KB
    __shared__ __align__(16) float  s_bias[D_];
    __shared__ __align__(16) float  s_dts[R_ * 68];    // [r][lt]    1.6 KB
    __shared__ __align__(16) float  s_B[TL * N_];      // [lt][n]    4.0 KB

    for (int i = tid; i < C_ * D_; i += 256) {
        int d = i / C_, c = i % C_;
        int cp = (c < 6) ? c : c + 2;
        s_wpT[d * 40 + cp] = xpw[(k * C_ + c) * D_ + d];
    }
    for (int i = tid; i < 96; i += 256) {
        s_wpT[i * 40 + 6] = 0.f;
        s_wpT[i * 40 + 7] = 0.f;
    }
    for (int i = tid; i < R_ * D_; i += 256) {
        int r = i / D_, d = i % D_;
        s_wdt[i] = wdt[(k * D_ + d) * R_ + r];
    }
    if (tid < D_) s_bias[tid] = bdt[k * D_ + tid];

    const __half* xsp = xs2 + (long)((k & 1) * B_ + b) * L_ * D_;
    for (int i = tid; i < TL * 24; i += 256) {
        int lt = i / 24, dq = i % 24;
        int row = (k < 2) ? (l0 + lt) : (L_ - 1 - l0 - lt);
        uint2 raw = *(const uint2*)(xsp + (long)row * D_ + dq * 4);
        const __half* hv = (const __half*)&raw;
        int d0 = dq * 4;
        s_xs[(d0 + 0) * 68 + (lt ^ SW(d0 + 0))] = hv[0];
        s_xs[(d0 + 1) * 68 + (lt ^ SW(d0 + 1))] = hv[1];
        s_xs[(d0 + 2) * 68 + (lt ^ SW(d0 + 2))] = hv[2];
        s_xs[(d0 + 3) * 68 + (lt ^ SW(d0 + 3))] = hv[3];
    }
    __syncthreads();

    long base = (long)bk * L_ + l0;

    // GEMM: 4x4 register tiles; 10 c-tiles x 16 lt-tiles = 160 threads
    int ct = tid >> 4;
    int lt4 = (tid & 15) * 4;
    if (ct < 10) {
        int cp0 = ct * 4;
        float acc[4][4];
#pragma unroll
        for (int i = 0; i < 4; ++i)
#pragma unroll
            for (int j = 0; j < 4; ++j) acc[i][j] = 0.f;
#pragma unroll 4
        for (int d = 0; d < D_; ++d) {
            float4 wv = *(const float4*)(&s_wpT[d * 40 + cp0]);
            float4 xv = load_h4(&s_xs[d * 68 + (lt4 ^ SW(d))]);
            float wa[4] = {wv.x, wv.y, wv.z, wv.w};
            float xa[4] = {xv.x, xv.y, xv.z, xv.w};
#pragma unroll
            for (int ci = 0; ci < 4; ++ci)
#pragma unroll
                for (int li = 0; li < 4; ++li)
                    acc[ci][li] += wa[ci] * xa[li];
        }
        if (ct == 0) {
#pragma unroll
            for (int ci = 0; ci < 4; ++ci)
                *(float4*)(&s_dts[ci * 68 + lt4]) =
                    make_float4(acc[ci][0], acc[ci][1], acc[ci][2], acc[ci][3]);
        } else if (ct == 1) {
#pragma unroll
            for (int ci = 0; ci < 2; ++ci)
                *(float4*)(&s_dts[(4 + ci) * 68 + lt4]) =
                    make_float4(acc[ci][0], acc[ci][1], acc[ci][2], acc[ci][3]);
        } else if (ct < 6) {
            int n0 = cp0 - 8;
#pragma unroll
            for (int li = 0; li < 4; ++li) {
                ushort4 hv;
                hv.x = f2h(acc[0][li]); hv.y = f2h(acc[1][li]);
                hv.z = f2h(acc[2][li]); hv.w = f2h(acc[3][li]);
                *(ushort4*)(&Bsb[(base + lt4 + li) * N_ + n0]) = hv;
                *(float4*)(&s_B[(lt4 + li) * N_ + n0]) =
                    make_float4(acc[0][li], acc[1][li], acc[2][li], acc[3][li]);
            }
        } else {
            int n0 = cp0 - 24;
#pragma unroll
            for (int li = 0; li < 4; ++li) {
                ushort4 hv;
                hv.x = f2h(acc[0][li]); hv.y = f2h(acc[1][li]);
                hv.z = f2h(acc[2][li]); hv.w = f2h(acc[3][li]);
                *(ushort4*)(&Csb[(base + lt4 + li) * N_ + n0]) = hv;
            }
        }
    }
    __syncthreads();

    // delta phase: 4x4 tiles, fp16 stores
    for (int tt = tid; tt < 24 * 16; tt += 256) {
        int dt = tt % 24, lt4b = (tt / 24) * 4;
        int d0 = dt * 4;
        float4 bias = *(const float4*)(&s_bias[d0]);
        float acc[4][4];
#pragma unroll
        for (int li = 0; li < 4; ++li) {
            acc[li][0] = bias.x; acc[li][1] = bias.y;
            acc[li][2] = bias.z; acc[li][3] = bias.w;
        }
#pragma unroll
        for (int r = 0; r < R_; ++r) {
            float4 wv = *(const float4*)(&s_wdt[r * D_ + d0]);
            float4 tv = *(const float4*)(&s_dts[r * 68 + lt4b]);
            float wa[4] = {wv.x, wv.y, wv.z, wv.w};
            float ta[4] = {tv.x, tv.y, tv.z, tv.w};
#pragma unroll
            for (int li = 0; li < 4; ++li)
#pragma unroll
                for (int di = 0; di < 4; ++di)
                    acc[li][di] += ta[li] * wa[di];
        }
#pragma unroll
        for (int li = 0; li < 4; ++li) {
            ushort4 o;
            o.x = f2h(softplus_f(acc[li][0]));
            o.y = f2h(softplus_f(acc[li][1]));
            o.z = f2h(softplus_f(acc[li][2]));
            o.w = f2h(softplus_f(acc[li][3]));
            *(ushort4*)(&delta[(base + lt4b + li) * D_ + d0]) = o;
        }
    }

    // Fused chunk scan (pass 1): threads 0..191 = 2 chunks x 96 dd, 16 states.
    if (tid < 192) {
        int sub = tid / 96;            // chunk within tile
        int dd = tid % 96;
        int j = tile * 2 + sub;
        int kd = k * D_ + dd;

        float A2[16];
        {
            const float4* ap = (const float4*)(A_logs + kd * N_);
#pragma unroll
            for (int q = 0; q < 4; ++q) {
                float4 a = ap[q];
                A2[q * 4 + 0] = -__expf(a.x) * LOG2E;
                A2[q * 4 + 1] = -__expf(a.y) * LOG2E;
                A2[q * 4 + 2] = -__expf(a.z) * LOG2E;
                A2[q * 4 + 3] = -__expf(a.w) * LOG2E;
            }
        }
        float wdtr[R_];
#pragma unroll
        for (int r = 0; r < R_; ++r) wdtr[r] = s_wdt[r * D_ + dd];
        float biasv = s_bias[dd];
        int sw = SW(dd);

        float h[16];
#pragma unroll
        for (int i = 0; i < 16; ++i) h[i] = 0.f;
        float sdel = 0.f;

#pragma unroll 4
        for (int t = 0; t < CLSX; ++t) {
            int lt = sub * CLSX + t;
            float acc = biasv;
#pragma unroll
            for (int r = 0; r < R_; ++r) acc += wdtr[r] * s_dts[r * 68 + lt];
            float del = softplus_f(acc);
            float u = __half2float(s_xs[dd * 68 + (lt ^ sw)]);
            float Bv[16];
            *(float4*)(Bv + 0)  = *(const float4*)(&s_B[lt * N_ + 0]);
            *(float4*)(Bv + 4)  = *(const float4*)(&s_B[lt * N_ + 4]);
            *(float4*)(Bv + 8)  = *(const float4*)(&s_B[lt * N_ + 8]);
            *(float4*)(Bv + 12) = *(const float4*)(&s_B[lt * N_ + 12]);
            sdel += del;
            float delu = del * u;
#pragma unroll
            for (int i = 0; i < 16; ++i) {
                float dA = EXP2F(del * A2[i]);
                h[i] = h[i] * dA + delu * Bv[i];
            }
        }

        long sbase = (long)j * CH_ + (long)(bk * D_ + dd) * N_;
        float pv[16];
#pragma unroll
        for (int i = 0; i < 16; ++i) pv[i] = EXP2F(A2[i] * sdel);
        store_h8(pAarr + sbase, pv);
        store_h8(pAarr + sbase + 8, pv + 8);
        store_h8(hharr + sbase, h);
        store_h8(hharr + sbase + 8, h + 8);
    }
}

// ---------------------------------------------------------------------------
// Pass 2: sequential combine over SSX chunk summaries (in-place, fp16 io).
// ---------------------------------------------------------------------------
__global__ __launch_bounds__(256) void scan_combine(
    const __half* __restrict__ pAarr,
    __half* __restrict__ hharr)
{
    int c = blockIdx.x * 256 + threadIdx.x;
    float h = 0.f;
#pragma unroll 16
    for (int j = 0; j < SSX; ++j) {
        long idx = (long)j * CH_ + c;
        float tmp = __half2float(hharr[idx]);
        float pa  = __half2float(pAarr[idx]);
        hharr[idx] = __float2half_rn(h);
        h = tmp + pa * h;
    }
}

// ---------------------------------------------------------------------------
// Pass 3: paired-direction re-scan, 8 states/thread; all-fp16 inputs.
// ---------------------------------------------------------------------------
__global__ __launch_bounds__(384) void scan_part2_pair(
    const float* __restrict__ A_logs,
    const float* __restrict__ Ds,
    const __half* __restrict__ xs2,
    const __half* __restrict__ delta,
    const __half* __restrict__ Bsb,
    const __half* __restrict__ Csb,
    const __half* __restrict__ hharr,
    float* __restrict__ ypair)   // (2, B, L, 96)
{
    __shared__ float s_y[2][CLSX][D_];   // 24.6 KB

    int bid = blockIdx.x;                // B*2*SSX = 1024
    int b = bid / (2 * SSX);
    int rest = bid % (2 * SSX);
    int p = rest / SSX;
    int j = rest % SSX;
    int tid = threadIdx.x;
    int g = tid / 192;
    int r = tid % 192;
    int dd = r >> 1;
    int half = r & 1;
    int n0 = half * 8;

    int kdir = p + 2 * g;
    int bk = b * K_ + kdir;
    int jj = g ? (SSX - 1 - j) : j;
    int l0s = jj * CLSX;
    int kd = kdir * D_ + dd;

    float A2[8];
    {
        const float4* ap = (const float4*)(A_logs + kd * N_ + n0);
        float4 a0 = ap[0], a1 = ap[1];
        A2[0] = -__expf(a0.x) * LOG2E; A2[1] = -__expf(a0.y) * LOG2E;
        A2[2] = -__expf(a0.z) * LOG2E; A2[3] = -__expf(a0.w) * LOG2E;
        A2[4] = -__expf(a1.x) * LOG2E; A2[5] = -__expf(a1.y) * LOG2E;
        A2[6] = -__expf(a1.z) * LOG2E; A2[7] = -__expf(a1.w) * LOG2E;
    }
    float Dv = Ds[kd];

    const __half* dp = delta + ((long)bk * L_ + l0s) * D_ + dd;
    const __half* bp = Bsb + ((long)bk * L_ + l0s) * N_ + n0;
    const __half* cp = Csb + ((long)bk * L_ + l0s) * N_ + n0;
    const __half* xsp = xs2 + (long)(p * B_ + b) * L_ * D_;
    long urow0 = g ? ((long)j * CLSX + CLSX - 1) : (long)l0s;
    long ustep = g ? -D_ : D_;
    const __half* up = xsp + urow0 * D_ + dd;

    float h[8];
    load_h8(hharr + (long)jj * CH_ + (long)(bk * D_ + dd) * N_ + n0, h);

#pragma unroll 4
    for (int t = 0; t < CLSX; ++t) {
        float del = __half2float(dp[(long)t * D_]);
        float u   = __half2float(up[(long)t * ustep]);
        float Bv[8], Cv[8];
        load_h8(bp + t * N_, Bv);
        load_h8(cp + t * N_, Cv);
        float delu = del * u;
        float yv = 0.f;
#pragma unroll
        for (int i = 0; i < 8; ++i) {
            float dA = EXP2F(del * A2[i]);
            h[i] = h[i] * dA + delu * Bv[i];
            yv += h[i] * Cv[i];
        }
        yv += __shfl_xor(yv, 1);   // sum the two n-halves (adjacent lanes)
        if (half == 0) {
            int tpos = g ? (CLSX - 1 - t) : t;
            s_y[g][tpos][dd] = yv + Dv * u;
        }
    }
    __syncthreads();

    float* yo = ypair + ((long)(p * B_ + b) * L_ + (long)j * CLSX) * D_;
    for (int i = tid; i < CLSX * 24; i += 384) {
        int lt = i / 24, dq = i % 24;
        int d0 = dq * 4;
        float4 o = make_float4(s_y[0][lt][d0 + 0] + s_y[1][lt][d0 + 0],
                               s_y[0][lt][d0 + 1] + s_y[1][lt][d0 + 1],
                               s_y[0][lt][d0 + 2] + s_y[1][lt][d0 + 2],
                               s_y[0][lt][d0 + 3] + s_y[1][lt][d0 + 3]);
        *(float4*)(yo + (long)lt * D_ + d0) = o;
    }
}

// ---------------------------------------------------------------------------
// Final: merge the two pair buffers (p=1 via transpose map) + LayerNorm.
// ---------------------------------------------------------------------------
__global__ __launch_bounds__(256) void ln_merge_kernel(
    const float* __restrict__ ypair,  // (2,B,L,96)
    const float* __restrict__ lnw,
    const float* __restrict__ lnb,
    float* __restrict__ out)          // (B,L,96)
{
    int wid = (blockIdx.x * 256 + threadIdx.x) >> 6;
    int lane = threadIdx.x & 63;
    int b = wid / L_;
    int m = wid % L_;
    int mt = ((m & 63) << 6) | (m >> 6);

    const float* y0 = ypair + ((long)b * L_ + m) * D_;
    const float* y1 = ypair + ((long)(B_ + b) * L_ + mt) * D_;

    float v0 = y0[lane] + y1[lane];
    float v1 = (lane < 32) ? (y0[64 + lane] + y1[64 + lane]) : 0.f;

    float s  = v0 + v1;
    float s2 = v0 * v0 + v1 * v1;
#pragma unroll
    for (int mm = 1; mm < 64; mm <<= 1) {
        s  += __shfl_xor(s, mm);
        s2 += __shfl_xor(s2, mm);
    }
    float mu  = s * (1.f / D_);
    float var = s2 * (1.f / D_) - mu * mu;
    float rstd = rsqrtf(var + 1e-5f);

    long obase = (long)wid * D_;
    out[obase + lane] = (v0 - mu) * rstd * lnw[lane] + lnb[lane];
    if (lane < 32)
        out[obase + 64 + lane] = (v1 - mu) * rstd * lnw[64 + lane] + lnb[64 + lane];
}

// ---------------------------------------------------------------------------
// Fallback path (only if ws too small): fp32 proj + serial scan + merge.
// ---------------------------------------------------------------------------
__global__ __launch_bounds__(256) void proj_legacy(
    const float* __restrict__ x,
    const float* __restrict__ xpw,
    const float* __restrict__ wdt,
    const float* __restrict__ bdt,
    float* __restrict__ delta,
    float* __restrict__ Bsb,
    float* __restrict__ Csb)
{
    const int TL = 64;
    const int tiles = L_ / TL;
    int bid = blockIdx.x;
    int bk = bid / tiles;
    int tile = bid % tiles;
    int b = bk / K_, k = bk % K_;
    int l0 = tile * TL;
    int tid = threadIdx.x;

    __shared__ float s_wp[C_ * D_];
    __shared__ float s_wdt[R_ * D_];
    __shared__ float s_bias[D_];
    __shared__ float s_xs[D_ * (TL + 1)];
    __shared__ float s_xdbl[C_ * (TL + 1)];

    for (int i = tid; i < C_ * D_; i += 256) s_wp[i] = xpw[k * C_ * D_ + i];
    for (int i = tid; i < R_ * D_; i += 256) {
        int r = i / D_, d = i % D_;
        s_wdt[i] = wdt[(k * D_ + d) * R_ + r];
    }
    if (tid < D_) s_bias[tid] = bdt[k * D_ + tid];
    for (int i = tid; i < D_ * TL; i += 256) {
        int d = i / TL, lt = i % TL;
        s_xs[d * (TL + 1) + lt] = x[(b * D_ + d) * L_ + src_idx(k, l0 + lt)];
    }
    __syncthreads();

    for (int idx = tid; idx < C_ * TL; idx += 256) {
        int c = idx / TL, lt = idx % TL;
        const float* wr = &s_wp[c * D_];
        float acc = 0.f;
#pragma unroll 8
        for (int d = 0; d < D_; ++d) acc += wr[d] * s_xs[d * (TL + 1) + lt];
        s_xdbl[c * (TL + 1) + lt] = acc;
    }
    __syncthreads();

    long base = (long)bk * L_ + l0;
    for (int idx = tid; idx < TL * D_; idx += 256) {
        int lt = idx / D_, d = idx % D_;
        float acc = s_bias[d];
#pragma unroll
        for (int r = 0; r < R_; ++r)
            acc += s_wdt[r * D_ + d] * s_xdbl[r * (TL + 1) + lt];
        delta[(base + lt) * D_ + d] = softplus_f(acc);
    }
    for (int idx = tid; idx < TL * 2 * N_; idx += 256) {
        int lt = idx / (2 * N_), c2 = idx % (2 * N_);
        float v = s_xdbl[(R_ + c2) * (TL + 1) + lt];
        if (c2 < N_) Bsb[(base + lt) * N_ + c2] = v;
        else         Csb[(base + lt) * N_ + (c2 - N_)] = v;
    }
}

__global__ __launch_bounds__(64) void scan_serial(
    const float* __restrict__ x,
    const float* __restrict__ A_logs,
    const float* __restrict__ Ds,
    const float* __restrict__ delta,
    const float* __restrict__ Bsb,
    const float* __restrict__ Csb,
    float* __restrict__ ys)
{
    const int chans = D_ / 4;
    int bid = blockIdx.x;
    int bk = bid / chans;
    int d0 = (bid % chans) * 4;
    int b = bk / K_, k = bk % K_;
    int lane = threadIdx.x;
    int g = lane >> 4, n = lane & 15;
    int d = d0 + g;
    int kd = k * D_ + d;

    float A  = -__expf(A_logs[kd * N_ + n]);
    float Dv = Ds[kd];
    const float* dptr = delta + ((long)bk * L_) * D_ + d;
    const float* bptr = Bsb + (long)bk * L_ * N_ + n;
    const float* cptr = Csb + (long)bk * L_ * N_ + n;
    const float* xptr = x + ((long)b * D_ + d) * L_;
    float* yptr = ys + ((long)bk * L_) * D_ + d;

    float h = 0.f;
#pragma unroll 4
    for (int l = 0; l < L_; ++l) {
        float del = dptr[(long)l * D_];
        float u   = xptr[src_idx(k, l)];
        float Bt  = bptr[l * N_];
        float Ct  = cptr[l * N_];
        float dA  = __expf(del * A);
        h = h * dA + del * u * Bt;
        float yv = h * Ct;
        yv += __shfl_xor(yv, 1);
        yv += __shfl_xor(yv, 2);
        yv += __shfl_xor(yv, 4);
        yv += __shfl_xor(yv, 8);
        if (n == 0) yptr[(long)l * D_] = yv + Dv * u;
    }
}

__global__ __launch_bounds__(256) void merge_ln_kernel(
    const float* __restrict__ ys,
    const float* __restrict__ lnw,
    const float* __restrict__ lnb,
    float* __restrict__ out)
{
    int wid = (blockIdx.x * 256 + threadIdx.x) >> 6;
    int lane = threadIdx.x & 63;
    int b = wid / L_;
    int l = wid % L_;
    int lt = ((l & 63) << 6) | (l >> 6);

    long base0 = ((long)(b * K_ + 0) * L_ + l) * D_;
    long base2 = ((long)(b * K_ + 2) * L_ + (L_ - 1 - l)) * D_;
    long base1 = ((long)(b * K_ + 1) * L_ + lt) * D_;
    long base3 = ((long)(b * K_ + 3) * L_ + (L_ - 1 - lt)) * D_;

    int dA = lane;
    int dB = lane + 64;
    float v0 = ys[base0 + dA] + ys[base2 + dA] + ys[base1 + dA] + ys[base3 + dA];
    float v1 = 0.f;
    if (dB < D_)
        v1 = ys[base0 + dB] + ys[base2 + dB] + ys[base1 + dB] + ys[base3 + dB];

    float s  = v0 + v1;
    float s2 = v0 * v0 + v1 * v1;
#pragma unroll
    for (int m = 1; m < 64; m <<= 1) {
        s  += __shfl_xor(s, m);
        s2 += __shfl_xor(s2, m);
    }
    float mu  = s * (1.f / D_);
    float var = s2 * (1.f / D_) - mu * mu;
    float rstd = rsqrtf(var + 1e-5f);

    long obase = ((long)b * L_ + l) * D_;
    out[obase + dA] = (v0 - mu) * rstd * lnw[dA] + lnb[dA];
    if (dB < D_)
        out[obase + dB] = (v1 - mu) * rstd * lnw[dB] + lnb[dB];
}

extern "C" void kernel_launch(void* const* d_in, const int* in_sizes, int n_in,
                              void* d_out, int out_size, void* d_ws, size_t ws_size,
                              hipStream_t stream) {
    const float* x      = (const float*)d_in[0];
    const float* xpw    = (const float*)d_in[1];
    const float* wdt    = (const float*)d_in[2];
    const float* bdt    = (const float*)d_in[3];
    const float* A_logs = (const float*)d_in[4];
    const float* Ds     = (const float*)d_in[5];
    const float* lnw    = (const float*)d_in[6];
    const float* lnb    = (const float*)d_in[7];
    float* out = (float*)d_out;

    const long n_delta = (long)B_ * K_ * L_ * D_;   // 6,291,456
    const long n_bc    = (long)B_ * K_ * L_ * N_;   // 1,048,576
    const long n_bld   = (long)B_ * L_ * D_;        // 1,572,864
    const long n_sum   = (long)SSX * CH_;           // 3,145,728

    // Byte layout: fp16 delta/B/C/xs2/summaries; fp32 ypair. 16B-aligned.
    char* wsb = (char*)d_ws;
    __half* delta = (__half*)wsb;                                  // 12.6 MB
    __half* Bsb   = (__half*)(wsb + n_delta * 2);                  //  2.1 MB
    __half* Csb   = (__half*)(wsb + n_delta * 2 + n_bc * 2);       //  2.1 MB
    __half* xs2   = (__half*)(wsb + n_delta * 2 + n_bc * 4);       //  6.3 MB
    float*  ypair = (float*)(wsb + n_delta * 2 + n_bc * 4 + 2 * n_bld * 2); // 12.6 MB
    __half* hharr = (__half*)((char*)ypair + 2 * n_bld * 4);       //  6.3 MB
    __half* pAarr = (__half*)ypair;  // alias: pA dead before ypair written
    size_t need = (size_t)(n_delta * 2 + n_bc * 4 + 2 * n_bld * 2) +
                  (size_t)(2 * n_bld) * 4 + (size_t)n_sum * 2;     // ~42 MB

    if (ws_size >= need) {
        transpose_kernel<<<B_ * 3 * 64, 256, 0, stream>>>(x, xs2);
        proj_scan_kernel<<<B_ * K_ * (L_ / 64), 256, 0, stream>>>(
            xs2, xpw, wdt, bdt, A_logs, delta, Bsb, Csb, pAarr, hharr);
        scan_combine<<<CH_ / 256, 256, 0, stream>>>(pAarr, hharr);
        scan_part2_pair<<<B_ * 2 * SSX, 384, 0, stream>>>(
            A_logs, Ds, xs2, delta, Bsb, Csb, hharr, ypair);
        ln_merge_kernel<<<(B_ * L_) / 4, 256, 0, stream>>>(ypair, lnw, lnb, out);
    } else {
        // Compact fp32 serial fallback (~58.7 MB layout)
        float* ws = (float*)d_ws;
        float* deltaf = ws;
        float* Bsb2   = deltaf + n_delta;
        float* Csb2   = Bsb2 + n_bc;
        float* ys2    = Csb2 + n_bc;
        proj_legacy<<<B_ * K_ * (L_ / 64), 256, 0, stream>>>(
            x, xpw, wdt, bdt, deltaf, Bsb2, Csb2);
        scan_serial<<<B_ * K_ * (D_ / 4), 64, 0, stream>>>(
            x, A_logs, Ds, deltaf, Bsb2, Csb2, ys2);
        merge_ln_kernel<<<(B_ * L_) / 4, 256, 0, stream>>>(ys2, lnw, lnb, out);
    }
}